// Round 23
// baseline (62.840 us; speedup 1.0000x reference)
//
#include <hip/hip_runtime.h>
#include <hip/hip_bf16.h>

typedef __attribute__((ext_vector_type(8))) short short8;
typedef __attribute__((ext_vector_type(4))) float f32x4;
typedef __attribute__((ext_vector_type(4))) unsigned short u16x4;
typedef unsigned short u16;

#define Bn 8
#define Tn 2048
#define Cn 1024
#define Hn 64
#define Mrows (Bn * Tn)  // 16384

__device__ __forceinline__ u16 bfu(float f) {
    __hip_bfloat16 h = __float2bfloat16(f);
    union { __hip_bfloat16 h; u16 u; } c; c.h = h; return c.u;
}

__device__ __forceinline__ short8 cvt8(f32x4 a0, f32x4 a1) {
    short8 r;
    r[0] = (short)bfu(a0[0]); r[1] = (short)bfu(a0[1]);
    r[2] = (short)bfu(a0[2]); r[3] = (short)bfu(a0[3]);
    r[4] = (short)bfu(a1[0]); r[5] = (short)bfu(a1[1]);
    r[6] = (short)bfu(a1[2]); r[7] = (short)bfu(a1[3]);
    return r;
}

// W [1024][64] f32 x3 -> wtf fragment-linear bf16 (round-9 layout).
__global__ void convert_w3(const float* __restrict__ Wq, const float* __restrict__ Wk,
                           const float* __restrict__ Wv, u16* __restrict__ wtf, float qscale) {
    int widx = blockIdx.x * 256 + threadIdx.x;          // 0 .. 196607
    int mat = widx >> 16;
    int rem = widx & 65535;
    int k = rem >> 6, n = rem & 63;
    const float* W = mat == 0 ? Wq : (mat == 1 ? Wk : Wv);
    float s = mat == 0 ? qscale : 1.0f;
    int ct = mat * 4 + (n >> 4);
    int lane = ((k >> 3) & 3) * 16 + (n & 15);
    wtf[(size_t)(ct * 32 + (k >> 5)) * 512 + lane * 8 + (k & 7)] = bfu(W[rem] * s);
}

// x [16384][1024] f32 @ W -> q/k/v fragment-linear.
// ROUND-22 POSTMORTEM: every barriered variant (1/2/4 blocks/CU, BM 16/32/64,
// 196/393MB B-traffic) pinned at ~37-41us; compiler drains vmcnt(0) at every
// __syncthreads -> 8 serialized full-latency exposures per block, unhideable
// at grid==co-residency. THIS KERNEL HAS NO BARRIERS: one wave per
// (16-row x 64-col x mat) unit, 3072 single-wave blocks (12 independent
// waves/CU), wave-private LDS A-tile (in-order LDS within a wave -> only
// lgkmcnt waits; global pipe never drains). x read 3x (L3-resident). Also
// fixes q/k stores: 2B scatters -> two coalesced 1KB frag stores via LDS
// re-stage (in-frag idx = ((d&31)>>3)*128 + row*8 + (d&7), round-9 algebra).
__global__ __launch_bounds__(64) void qkv_proj(const float* __restrict__ x,
                                               const u16* __restrict__ wtf,
                                               u16* __restrict__ qfl,
                                               u16* __restrict__ kfl,
                                               u16* __restrict__ vfl) {
    __shared__ u16 As[16][136];   // wave-private A tile (bf16), 4352 B
    __shared__ u16 ep[16][68];    // epilogue re-stage (q/k), 2176 B
    const int lane = threadIdx.x;
    const int l15 = lane & 15, lhi = lane >> 4;
    const int bid = (int)blockIdx.x;        // 0..3071
    const int tile = bid / 3;               // 0..1023 (consecutive bids share x rows)
    const int mat = bid - tile * 3;         // 0..2
    const int row0 = tile * 16;

    const int srow = lane >> 4;             // 0..3 (row within 4-row group)
    const int scol = (lane & 15) * 8;       // f32 col 0..120

    f32x4 acc[4];
    #pragma unroll
    for (int nj = 0; nj < 4; ++nj) acc[nj] = f32x4{0.f, 0.f, 0.f, 0.f};

    #pragma unroll
    for (int ks = 0; ks < 8; ++ks) {
        // stage A: 4 row-groups, coalesced (4 rows x 512B per instr pair)
        #pragma unroll
        for (int i = 0; i < 4; ++i) {
            const float* src = x + (size_t)(row0 + i * 4 + srow) * Cn + ks * 128 + scol;
            f32x4 a = *(const f32x4*)src;
            f32x4 b = *(const f32x4*)(src + 4);
            *(short8*)&As[i * 4 + srow][scol] = cvt8(a, b);
        }
        // in-order LDS within the wave: reads below see the writes above
        #pragma unroll
        for (int kc = 0; kc < 4; ++kc) {
            short8 af = *(const short8*)&As[l15][kc * 32 + lhi * 8];
            #pragma unroll
            for (int nj = 0; nj < 4; ++nj) {
                short8 bf = *(const short8*)(wtf + (size_t)((mat * 4 + nj) * 32 + ks * 4 + kc) * 512 + lane * 8);
                acc[nj] = __builtin_amdgcn_mfma_f32_16x16x32_bf16(af, bf, acc[nj], 0, 0, 0);
            }
        }
    }

    // ---- epilogue ----
    const int bI = row0 >> 11;              // batch
    const int tloc = row0 & 2047;
    if (mat < 2) {
        // stage acc (row = lhi*4+r, d = nj*16+l15) into ep[row][d]
        #pragma unroll
        for (int nj = 0; nj < 4; ++nj)
            #pragma unroll
            for (int r = 0; r < 4; ++r)
                ep[lhi * 4 + r][nj * 16 + l15] = bfu(acc[nj][r]);
        // two coalesced 1KB frag stores: lane = lhid*16 + trow
        u16* dst = (mat == 0 ? qfl : kfl) + (size_t)bI * 131072;
        const int g = tloc >> 4;
        const int trow = lane & 15, lhid = lane >> 4;
        #pragma unroll
        for (int kcf = 0; kcf < 2; ++kcf) {
            short8 v8 = *(const short8*)&ep[trow][kcf * 32 + lhid * 8];
            *(short8*)(dst + ((size_t)(g * 2 + kcf)) * 512 + lane * 8) = v8;
        }
    } else {
        // v path: round-9 verified u16x4 formula (dt = nj)
        const int growb = tloc + lhi * 4;
        const int kt64 = growb >> 6;
        const int tin = growb & 63;
        const int kcv = tin >> 5;
        const int lhiv = (tin & 31) >> 3;
        const int e0 = tin & 7;             // in {0,4}
        #pragma unroll
        for (int nj = 0; nj < 4; ++nj) {
            u16x4 pk;
            pk[0] = bfu(acc[nj][0]); pk[1] = bfu(acc[nj][1]);
            pk[2] = bfu(acc[nj][2]); pk[3] = bfu(acc[nj][3]);
            *(u16x4*)(vfl + ((size_t)((bI * 32 + kt64) * 4 + nj) * 2 + kcv) * 512
                          + (size_t)(lhiv * 16 + l15) * 8 + e0) = pk;
        }
    }
}

// Flash attention, causal. Block-level split-K, 8 waves per 16-row q-tile
// (round-17 verified, byte-identical; ~7us in-situ).
__global__ __launch_bounds__(512, 4) void attn_fwd(const u16* __restrict__ qfl,
                                                   const u16* __restrict__ kfl,
                                                   const u16* __restrict__ vfl,
                                                   float* __restrict__ out) {
    __shared__ float o_lds[8][16][68];
    __shared__ float ml_lds[8][2][16];
    __shared__ u16 pl[8][16][72];
    const int tid = threadIdx.x;
    const int lane = tid & 63;
    const int w = tid >> 6;           // 0..7
    const int l15 = lane & 15, lhi = lane >> 4;
    const int idx = (int)blockIdx.x;  // 0..1023
    const int qt = 127 - (idx >> 3);  // longest q-tiles dispatched first
    const int b = idx & 7;
    const int nkt = (qt >> 2) + 1;
    const int q0 = qt * 16;

    const u16* qb = qfl + (size_t)b * 131072;
    const u16* kb = kfl + (size_t)b * 131072;
    const u16* vb = vfl + (size_t)b * 131072;

    short8 qf[2];
    #pragma unroll
    for (int kc = 0; kc < 2; ++kc)
        qf[kc] = *(const short8*)(qb + ((size_t)(qt * 2 + kc) * 64 + lane) * 8);

    float m = -1e30f, lpart = 0.f;
    f32x4 o[4];
    for (int dt = 0; dt < 4; ++dt) o[dt] = f32x4{0.f, 0.f, 0.f, 0.f};

    for (int kbi = w; kbi < nkt; kbi += 8) {
        const int k0 = kbi * 64;
        short8 kf[2][4], vf[4][2];
        #pragma unroll
        for (int kc = 0; kc < 2; ++kc)
            #pragma unroll
            for (int kt = 0; kt < 4; ++kt)
                kf[kc][kt] = *(const short8*)(kb + ((size_t)((kbi * 4 + kt) * 2 + kc) * 64 + lane) * 8);
        #pragma unroll
        for (int dt = 0; dt < 4; ++dt)
            #pragma unroll
            for (int kc = 0; kc < 2; ++kc)
                vf[dt][kc] = *(const short8*)(vb + ((size_t)((kbi * 4 + dt) * 2 + kc) * 512 + lane * 8));

        f32x4 sacc[4];
        for (int kt = 0; kt < 4; ++kt) sacc[kt] = f32x4{0.f, 0.f, 0.f, 0.f};
        #pragma unroll
        for (int kc = 0; kc < 2; ++kc)
            #pragma unroll
            for (int kt = 0; kt < 4; ++kt)
                sacc[kt] = __builtin_amdgcn_mfma_f32_16x16x32_bf16(kf[kc][kt], qf[kc], sacc[kt], 0, 0, 0);

        if (kbi == nkt - 1) {             // diagonal: causal mask
            for (int kt = 0; kt < 4; ++kt)
                for (int r = 0; r < 4; ++r) {
                    int kg = k0 + kt * 16 + lhi * 4 + r;
                    if (kg > q0 + l15) sacc[kt][r] = -3.0e38f;
                }
        }
        f32x4 mx0, mx1;
        for (int e = 0; e < 4; ++e) {
            mx0[e] = fmaxf(sacc[0][e], sacc[1][e]);
            mx1[e] = fmaxf(sacc[2][e], sacc[3][e]);
        }
        float tmax = -3.0e38f;
        for (int e = 0; e < 4; ++e) tmax = fmaxf(tmax, fmaxf(mx0[e], mx1[e]));
        tmax = fmaxf(tmax, __shfl_xor(tmax, 16));
        tmax = fmaxf(tmax, __shfl_xor(tmax, 32));
        if (!__all(tmax <= m + 8.0f)) {   // defer-max (THR=8, log2 domain)
            float mnew = fmaxf(m, tmax);
            float corr = exp2f(m - mnew);
            m = mnew;
            lpart *= corr;
            for (int r = 0; r < 4; ++r) {
                float cr = __shfl(corr, lhi * 4 + r);
                for (int dt = 0; dt < 4; ++dt) o[dt][r] *= cr;
            }
        }
        float psum = 0.f;
        for (int kt = 0; kt < 4; ++kt)
            for (int r = 0; r < 4; ++r) {
                float p = exp2f(sacc[kt][r] - m);
                sacc[kt][r] = p;
                psum += p;
            }
        lpart += psum;
        for (int kt = 0; kt < 4; ++kt) {
            u16x4 pk;
            pk[0] = bfu(sacc[kt][0]); pk[1] = bfu(sacc[kt][1]);
            pk[2] = bfu(sacc[kt][2]); pk[3] = bfu(sacc[kt][3]);
            *(u16x4*)&pl[w][l15][kt * 16 + lhi * 4] = pk;
        }
        short8 pf[2];
        #pragma unroll
        for (int kc = 0; kc < 2; ++kc)
            pf[kc] = *(const short8*)&pl[w][l15][kc * 32 + lhi * 8];
        #pragma unroll
        for (int dt = 0; dt < 4; ++dt)
            #pragma unroll
            for (int kc = 0; kc < 2; ++kc)
                o[dt] = __builtin_amdgcn_mfma_f32_16x16x32_bf16(pf[kc], vf[dt][kc], o[dt], 0, 0, 0);
    }
    float lsum = lpart;
    lsum += __shfl_xor(lsum, 16);
    lsum += __shfl_xor(lsum, 32);

    for (int dt = 0; dt < 4; ++dt)
        for (int r = 0; r < 4; ++r)
            o_lds[w][lhi * 4 + r][dt * 16 + l15] = o[dt][r];
    if (lhi == 0) {
        ml_lds[w][0][l15] = m;
        ml_lds[w][1][l15] = lsum;
    }
    __syncthreads();

    float* ob = out + ((size_t)b * Tn + q0) * Hn;
    #pragma unroll
    for (int i = 0; i < 2; ++i) {
        const int e = tid + 512 * i;      // 0..1023
        const int row = e >> 6, d = e & 63;
        float M = -3.0e38f;
        #pragma unroll
        for (int ww = 0; ww < 8; ++ww) M = fmaxf(M, ml_lds[ww][0][row]);
        float L = 0.f, acc = 0.f;
        #pragma unroll
        for (int ww = 0; ww < 8; ++ww) {
            float wgt = exp2f(ml_lds[ww][0][row] - M);
            L += ml_lds[ww][1][row] * wgt;
            acc += o_lds[ww][row][d] * wgt;
        }
        ob[(size_t)row * Hn + d] = acc / L;
    }
}

extern "C" void kernel_launch(void* const* d_in, const int* in_sizes, int n_in,
                              void* d_out, int out_size, void* d_ws, size_t ws_size,
                              hipStream_t stream) {
    const float* x = (const float*)d_in[0];
    const float* Wq = (const float*)d_in[1];
    const float* Wk = (const float*)d_in[2];
    const float* Wv = (const float*)d_in[3];
    float* out = (float*)d_out;
    char* ws = (char*)d_ws;

    u16* wtf = (u16*)ws;                                   // 384 KB
    u16* qfl = (u16*)(ws + 196608 * 2);                    // 2 MB
    u16* kfl = qfl + (size_t)Bn * 131072;                  // 2 MB
    u16* vfl = kfl + (size_t)Bn * 131072;                  // 2 MB

    const float qscale = 0.04508422002778011f;  // C^-0.5 * log2(e)
    convert_w3<<<768, 256, 0, stream>>>(Wq, Wk, Wv, wtf, qscale);
    qkv_proj<<<3072, 64, 0, stream>>>(x, wtf, qfl, kfl, vfl);
    attn_fwd<<<1024, 512, 0, stream>>>(qfl, kfl, vfl, out);
}

// Round 24
// 55.767 us; speedup vs baseline: 1.1268x; 1.1268x over previous
//
#include <hip/hip_runtime.h>
#include <hip/hip_bf16.h>

typedef __attribute__((ext_vector_type(8))) short short8;
typedef __attribute__((ext_vector_type(4))) float f32x4;
typedef __attribute__((ext_vector_type(4))) unsigned short u16x4;
typedef unsigned short u16;

#define Bn 8
#define Tn 2048
#define Cn 1024
#define Hn 64
#define Mrows (Bn * Tn)  // 16384

__device__ __forceinline__ u16 bfu(float f) {
    __hip_bfloat16 h = __float2bfloat16(f);
    union { __hip_bfloat16 h; u16 u; } c; c.h = h; return c.u;
}

__device__ __forceinline__ short8 cvt8(f32x4 a0, f32x4 a1) {
    short8 r;
    r[0] = (short)bfu(a0[0]); r[1] = (short)bfu(a0[1]);
    r[2] = (short)bfu(a0[2]); r[3] = (short)bfu(a0[3]);
    r[4] = (short)bfu(a1[0]); r[5] = (short)bfu(a1[1]);
    r[6] = (short)bfu(a1[2]); r[7] = (short)bfu(a1[3]);
    return r;
}

// Non-temporal f32x4 load: nt flag bypasses L2 allocation (x/W are stream-once;
// round-23 postmortem: streaming x through L2 evicts the 384KB wtf -> every
// B-frag load becomes a serialized ~600-900cy far-hit -> the invariant
// ~12k cy/K-step across ALL qkv structures).
__device__ __forceinline__ f32x4 ntl4(const float* p) {
    return __builtin_nontemporal_load((const f32x4*)p);
}

// W [1024][64] f32 x3 -> wtf fragment-linear bf16 (round-9 layout).
__global__ void convert_w3(const float* __restrict__ Wq, const float* __restrict__ Wk,
                           const float* __restrict__ Wv, u16* __restrict__ wtf, float qscale) {
    int widx = blockIdx.x * 256 + threadIdx.x;          // 0 .. 196607
    int mat = widx >> 16;
    int rem = widx & 65535;
    int k = rem >> 6, n = rem & 63;
    const float* W = mat == 0 ? Wq : (mat == 1 ? Wk : Wv);
    float s = mat == 0 ? qscale : 1.0f;
    int ct = mat * 4 + (n >> 4);
    int lane = ((k >> 3) & 3) * 16 + (n & 15);
    float wv = __builtin_nontemporal_load(W + rem);
    wtf[(size_t)(ct * 32 + (k >> 5)) * 512 + lane * 8 + (k & 7)] = bfu(wv * s);
}

// x [16384][1024] f32 @ W -> q/k/v fragment-linear. Round-19 structure
// (verified best, 47.5us total): 4 waves, BM=32, BK=128, double-buffered LDS
// A, one barrier/K-step, B-frags coalesced from wtf. ONE change: x loads are
// NON-TEMPORAL so the x stream no longer evicts wtf from the per-XCD L2.
__global__ __launch_bounds__(256, 4) void qkv_proj(const float* __restrict__ x,
                                                   const u16* __restrict__ wtf,
                                                   u16* __restrict__ qfl,
                                                   u16* __restrict__ kfl,
                                                   u16* __restrict__ vfl) {
    __shared__ u16 As[2][32][136];
    const int tid = threadIdx.x;
    const int lane = tid & 63;
    const int wn = tid >> 6;          // 0..3 -> 48-col slice (distinct per wave)
    const int l15 = lane & 15;
    const int lhi = lane >> 4;
    const int row0 = blockIdx.x * 32;

    const int arow = tid >> 3;        // 0..31
    const int ac0 = (tid & 7) * 16;   // f32 col base 0..112 (16 f32/thread)
    const float* asrc = x + (size_t)(row0 + arow) * Cn + ac0;

    f32x4 acc[2][3];
    for (int mt = 0; mt < 2; ++mt)
        for (int nj = 0; nj < 3; ++nj) acc[mt][nj] = f32x4{0.f, 0.f, 0.f, 0.f};

    // prologue: buf0 <- ks0; regs <- ks1
    f32x4 r0 = ntl4(asrc);
    f32x4 r1 = ntl4(asrc + 4);
    f32x4 r2 = ntl4(asrc + 8);
    f32x4 r3 = ntl4(asrc + 12);
    *(short8*)&As[0][arow][ac0]     = cvt8(r0, r1);
    *(short8*)&As[0][arow][ac0 + 8] = cvt8(r2, r3);
    r0 = ntl4(asrc + 128);
    r1 = ntl4(asrc + 132);
    r2 = ntl4(asrc + 136);
    r3 = ntl4(asrc + 140);
    __syncthreads();

    for (int ks = 0; ks < 8; ++ks) {
        const int cur = ks & 1;
        if (ks < 7) {
            *(short8*)&As[cur ^ 1][arow][ac0]     = cvt8(r0, r1);
            *(short8*)&As[cur ^ 1][arow][ac0 + 8] = cvt8(r2, r3);
            if (ks < 6) {
                const float* nsrc = asrc + (size_t)(ks + 2) * 128;
                r0 = ntl4(nsrc);
                r1 = ntl4(nsrc + 4);
                r2 = ntl4(nsrc + 8);
                r3 = ntl4(nsrc + 12);
            }
        }
        #pragma unroll
        for (int kc = 0; kc < 4; ++kc) {
            short8 af0 = *(const short8*)&As[cur][l15][kc * 32 + lhi * 8];
            short8 af1 = *(const short8*)&As[cur][16 + l15][kc * 32 + lhi * 8];
            #pragma unroll
            for (int nj = 0; nj < 3; ++nj) {
                short8 bf = *(const short8*)(wtf + (size_t)((wn * 3 + nj) * 32 + ks * 4 + kc) * 512 + lane * 8);
                acc[0][nj] = __builtin_amdgcn_mfma_f32_16x16x32_bf16(af0, bf, acc[0][nj], 0, 0, 0);
                acc[1][nj] = __builtin_amdgcn_mfma_f32_16x16x32_bf16(af1, bf, acc[1][nj], 0, 0, 0);
            }
        }
        __syncthreads();
    }

    // epilogue: scatter into fragment-linear q/k/v (round-9 verified algebra)
    for (int mt = 0; mt < 2; ++mt) {
        const int growb = row0 + mt * 16 + lhi * 4;    // t = growb + r
        const int bI = growb >> 11;
        const int tloc = growb & 2047;
        for (int nj = 0; nj < 3; ++nj) {
            const int gcolb = wn * 48 + nj * 16;
            const int matid = gcolb >> 6;
            const int d0 = gcolb & 63;
            if (matid < 2) {
                u16* dst = matid == 0 ? qfl : kfl;
                const int g = tloc >> 4;
                const int lhid = ((d0 & 31) + l15) >> 3;
                const size_t base = ((size_t)(bI * 128 + g) * 2 + (d0 >> 5)) * 512
                                    + (size_t)lhid * 128 + (l15 & 7);
                for (int r = 0; r < 4; ++r)
                    dst[base + (size_t)(lhi * 4 + r) * 8] = bfu(acc[mt][nj][r]);
            } else {
                const int kt64 = tloc >> 6;
                const int tin = tloc & 63;
                const int kcv = tin >> 5;
                const int lhiv = (tin & 31) >> 3;
                const int e0 = tin & 7;
                const int dt = d0 >> 4;
                u16x4 pk;
                pk[0] = bfu(acc[mt][nj][0]); pk[1] = bfu(acc[mt][nj][1]);
                pk[2] = bfu(acc[mt][nj][2]); pk[3] = bfu(acc[mt][nj][3]);
                *(u16x4*)(vfl + ((size_t)((bI * 32 + kt64) * 4 + dt) * 2 + kcv) * 512
                              + (size_t)(lhiv * 16 + l15) * 8 + e0) = pk;
            }
        }
    }
}

// Flash attention, causal. Block-level split-K, 8 waves per 16-row q-tile
// (round-17 verified, byte-identical; ~7us in-situ).
__global__ __launch_bounds__(512, 4) void attn_fwd(const u16* __restrict__ qfl,
                                                   const u16* __restrict__ kfl,
                                                   const u16* __restrict__ vfl,
                                                   float* __restrict__ out) {
    __shared__ float o_lds[8][16][68];
    __shared__ float ml_lds[8][2][16];
    __shared__ u16 pl[8][16][72];
    const int tid = threadIdx.x;
    const int lane = tid & 63;
    const int w = tid >> 6;           // 0..7
    const int l15 = lane & 15, lhi = lane >> 4;
    const int idx = (int)blockIdx.x;  // 0..1023
    const int qt = 127 - (idx >> 3);  // longest q-tiles dispatched first
    const int b = idx & 7;
    const int nkt = (qt >> 2) + 1;
    const int q0 = qt * 16;

    const u16* qb = qfl + (size_t)b * 131072;
    const u16* kb = kfl + (size_t)b * 131072;
    const u16* vb = vfl + (size_t)b * 131072;

    short8 qf[2];
    #pragma unroll
    for (int kc = 0; kc < 2; ++kc)
        qf[kc] = *(const short8*)(qb + ((size_t)(qt * 2 + kc) * 64 + lane) * 8);

    float m = -1e30f, lpart = 0.f;
    f32x4 o[4];
    for (int dt = 0; dt < 4; ++dt) o[dt] = f32x4{0.f, 0.f, 0.f, 0.f};

    for (int kbi = w; kbi < nkt; kbi += 8) {
        const int k0 = kbi * 64;
        short8 kf[2][4], vf[4][2];
        #pragma unroll
        for (int kc = 0; kc < 2; ++kc)
            #pragma unroll
            for (int kt = 0; kt < 4; ++kt)
                kf[kc][kt] = *(const short8*)(kb + ((size_t)((kbi * 4 + kt) * 2 + kc) * 64 + lane) * 8);
        #pragma unroll
        for (int dt = 0; dt < 4; ++dt)
            #pragma unroll
            for (int kc = 0; kc < 2; ++kc)
                vf[dt][kc] = *(const short8*)(vb + ((size_t)((kbi * 4 + dt) * 2 + kc) * 512 + lane * 8));

        f32x4 sacc[4];
        for (int kt = 0; kt < 4; ++kt) sacc[kt] = f32x4{0.f, 0.f, 0.f, 0.f};
        #pragma unroll
        for (int kc = 0; kc < 2; ++kc)
            #pragma unroll
            for (int kt = 0; kt < 4; ++kt)
                sacc[kt] = __builtin_amdgcn_mfma_f32_16x16x32_bf16(kf[kc][kt], qf[kc], sacc[kt], 0, 0, 0);

        if (kbi == nkt - 1) {             // diagonal: causal mask
            for (int kt = 0; kt < 4; ++kt)
                for (int r = 0; r < 4; ++r) {
                    int kg = k0 + kt * 16 + lhi * 4 + r;
                    if (kg > q0 + l15) sacc[kt][r] = -3.0e38f;
                }
        }
        f32x4 mx0, mx1;
        for (int e = 0; e < 4; ++e) {
            mx0[e] = fmaxf(sacc[0][e], sacc[1][e]);
            mx1[e] = fmaxf(sacc[2][e], sacc[3][e]);
        }
        float tmax = -3.0e38f;
        for (int e = 0; e < 4; ++e) tmax = fmaxf(tmax, fmaxf(mx0[e], mx1[e]));
        tmax = fmaxf(tmax, __shfl_xor(tmax, 16));
        tmax = fmaxf(tmax, __shfl_xor(tmax, 32));
        if (!__all(tmax <= m + 8.0f)) {   // defer-max (THR=8, log2 domain)
            float mnew = fmaxf(m, tmax);
            float corr = exp2f(m - mnew);
            m = mnew;
            lpart *= corr;
            for (int r = 0; r < 4; ++r) {
                float cr = __shfl(corr, lhi * 4 + r);
                for (int dt = 0; dt < 4; ++dt) o[dt][r] *= cr;
            }
        }
        float psum = 0.f;
        for (int kt = 0; kt < 4; ++kt)
            for (int r = 0; r < 4; ++r) {
                float p = exp2f(sacc[kt][r] - m);
                sacc[kt][r] = p;
                psum += p;
            }
        lpart += psum;
        for (int kt = 0; kt < 4; ++kt) {
            u16x4 pk;
            pk[0] = bfu(sacc[kt][0]); pk[1] = bfu(sacc[kt][1]);
            pk[2] = bfu(sacc[kt][2]); pk[3] = bfu(sacc[kt][3]);
            *(u16x4*)&pl[w][l15][kt * 16 + lhi * 4] = pk;
        }
        short8 pf[2];
        #pragma unroll
        for (int kc = 0; kc < 2; ++kc)
            pf[kc] = *(const short8*)&pl[w][l15][kc * 32 + lhi * 8];
        #pragma unroll
        for (int dt = 0; dt < 4; ++dt)
            #pragma unroll
            for (int kc = 0; kc < 2; ++kc)
                o[dt] = __builtin_amdgcn_mfma_f32_16x16x32_bf16(pf[kc], vf[dt][kc], o[dt], 0, 0, 0);
    }
    float lsum = lpart;
    lsum += __shfl_xor(lsum, 16);
    lsum += __shfl_xor(lsum, 32);

    for (int dt = 0; dt < 4; ++dt)
        for (int r = 0; r < 4; ++r)
            o_lds[w][lhi * 4 + r][dt * 16 + l15] = o[dt][r];
    if (lhi == 0) {
        ml_lds[w][0][l15] = m;
        ml_lds[w][1][l15] = lsum;
    }
    __syncthreads();

    float* ob = out + ((size_t)b * Tn + q0) * Hn;
    #pragma unroll
    for (int i = 0; i < 2; ++i) {
        const int e = tid + 512 * i;      // 0..1023
        const int row = e >> 6, d = e & 63;
        float M = -3.0e38f;
        #pragma unroll
        for (int ww = 0; ww < 8; ++ww) M = fmaxf(M, ml_lds[ww][0][row]);
        float L = 0.f, acc = 0.f;
        #pragma unroll
        for (int ww = 0; ww < 8; ++ww) {
            float wgt = exp2f(ml_lds[ww][0][row] - M);
            L += ml_lds[ww][1][row] * wgt;
            acc += o_lds[ww][row][d] * wgt;
        }
        ob[(size_t)row * Hn + d] = acc / L;
    }
}

extern "C" void kernel_launch(void* const* d_in, const int* in_sizes, int n_in,
                              void* d_out, int out_size, void* d_ws, size_t ws_size,
                              hipStream_t stream) {
    const float* x = (const float*)d_in[0];
    const float* Wq = (const float*)d_in[1];
    const float* Wk = (const float*)d_in[2];
    const float* Wv = (const float*)d_in[3];
    float* out = (float*)d_out;
    char* ws = (char*)d_ws;

    u16* wtf = (u16*)ws;                                   // 384 KB
    u16* qfl = (u16*)(ws + 196608 * 2);                    // 2 MB
    u16* kfl = qfl + (size_t)Bn * 131072;                  // 2 MB
    u16* vfl = kfl + (size_t)Bn * 131072;                  // 2 MB

    const float qscale = 0.04508422002778011f;  // C^-0.5 * log2(e)
    convert_w3<<<768, 256, 0, stream>>>(Wq, Wk, Wv, wtf, qscale);
    qkv_proj<<<Mrows / 32, 256, 0, stream>>>(x, wtf, qfl, kfl, vfl);
    attn_fwd<<<1024, 512, 0, stream>>>(qfl, kfl, vfl, out);
}

// Round 25
// 47.264 us; speedup vs baseline: 1.3295x; 1.1799x over previous
//
#include <hip/hip_runtime.h>
#include <hip/hip_bf16.h>

typedef __attribute__((ext_vector_type(8))) short short8;
typedef __attribute__((ext_vector_type(4))) float f32x4;
typedef __attribute__((ext_vector_type(4))) unsigned short u16x4;
typedef unsigned short u16;

#define Bn 8
#define Tn 2048
#define Cn 1024
#define Hn 64
#define Mrows (Bn * Tn)  // 16384

// Barrier that does NOT drain the global-load queue (round-24 postmortem:
// __syncthreads compiles to s_waitcnt vmcnt(0) before s_barrier — every
// K-step's prefetch was forcibly drained, collapsing MLP; explains the
// ~47.5us invariance across occupancy/prefetch/traffic variants R14-R23).
// lgkmcnt(0) makes our ds_writes visible to other waves; vmcnt survives.
#define BARRIER_KEEP_VMCNT() do { \
    asm volatile("s_waitcnt lgkmcnt(0)" ::: "memory"); \
    __builtin_amdgcn_s_barrier(); \
} while (0)

__device__ __forceinline__ u16 bfu(float f) {
    __hip_bfloat16 h = __float2bfloat16(f);
    union { __hip_bfloat16 h; u16 u; } c; c.h = h; return c.u;
}

__device__ __forceinline__ short8 cvt8(f32x4 a0, f32x4 a1) {
    short8 r;
    r[0] = (short)bfu(a0[0]); r[1] = (short)bfu(a0[1]);
    r[2] = (short)bfu(a0[2]); r[3] = (short)bfu(a0[3]);
    r[4] = (short)bfu(a1[0]); r[5] = (short)bfu(a1[1]);
    r[6] = (short)bfu(a1[2]); r[7] = (short)bfu(a1[3]);
    return r;
}

// W [1024][64] f32 x3 -> wtf fragment-linear bf16 (round-9 layout).
__global__ void convert_w3(const float* __restrict__ Wq, const float* __restrict__ Wk,
                           const float* __restrict__ Wv, u16* __restrict__ wtf, float qscale) {
    int widx = blockIdx.x * 256 + threadIdx.x;          // 0 .. 196607
    int mat = widx >> 16;
    int rem = widx & 65535;
    int k = rem >> 6, n = rem & 63;
    const float* W = mat == 0 ? Wq : (mat == 1 ? Wk : Wv);
    float s = mat == 0 ? qscale : 1.0f;
    int ct = mat * 4 + (n >> 4);
    int lane = ((k >> 3) & 3) * 16 + (n & 15);
    wtf[(size_t)(ct * 32 + (k >> 5)) * 512 + lane * 8 + (k & 7)] = bfu(W[rem] * s);
}

// x [16384][1024] f32 @ W -> q/k/v fragment-linear. Round-19 verified base
// (4 waves, BM=32, BK=128, double-buffered LDS A, B-frags coalesced from wtf),
// ONE change: in-loop barriers keep vmcnt alive so the ks+2 x-prefetch stays
// in flight across them (compiler's own counted vmcnt gates the ds_write).
__global__ __launch_bounds__(256, 4) void qkv_proj(const float* __restrict__ x,
                                                   const u16* __restrict__ wtf,
                                                   u16* __restrict__ qfl,
                                                   u16* __restrict__ kfl,
                                                   u16* __restrict__ vfl) {
    __shared__ u16 As[2][32][136];
    const int tid = threadIdx.x;
    const int lane = tid & 63;
    const int wn = tid >> 6;          // 0..3 -> 48-col slice (distinct per wave)
    const int l15 = lane & 15;
    const int lhi = lane >> 4;
    const int row0 = blockIdx.x * 32;

    const int arow = tid >> 3;        // 0..31
    const int ac0 = (tid & 7) * 16;   // f32 col base 0..112 (16 f32/thread)
    const float* asrc = x + (size_t)(row0 + arow) * Cn + ac0;

    f32x4 acc[2][3];
    for (int mt = 0; mt < 2; ++mt)
        for (int nj = 0; nj < 3; ++nj) acc[mt][nj] = f32x4{0.f, 0.f, 0.f, 0.f};

    // prologue: buf0 <- ks0; regs <- ks1
    f32x4 r0 = *(const f32x4*)(asrc);
    f32x4 r1 = *(const f32x4*)(asrc + 4);
    f32x4 r2 = *(const f32x4*)(asrc + 8);
    f32x4 r3 = *(const f32x4*)(asrc + 12);
    *(short8*)&As[0][arow][ac0]     = cvt8(r0, r1);
    *(short8*)&As[0][arow][ac0 + 8] = cvt8(r2, r3);
    r0 = *(const f32x4*)(asrc + 128);
    r1 = *(const f32x4*)(asrc + 132);
    r2 = *(const f32x4*)(asrc + 136);
    r3 = *(const f32x4*)(asrc + 140);
    BARRIER_KEEP_VMCNT();

    for (int ks = 0; ks < 8; ++ks) {
        const int cur = ks & 1;
        if (ks < 7) {
            // compiler inserts a COUNTED vmcnt wait here (dep on r0..r3 only)
            *(short8*)&As[cur ^ 1][arow][ac0]     = cvt8(r0, r1);
            *(short8*)&As[cur ^ 1][arow][ac0 + 8] = cvt8(r2, r3);
            if (ks < 6) {
                const float* nsrc = asrc + (size_t)(ks + 2) * 128;
                r0 = *(const f32x4*)(nsrc);
                r1 = *(const f32x4*)(nsrc + 4);
                r2 = *(const f32x4*)(nsrc + 8);
                r3 = *(const f32x4*)(nsrc + 12);
            }
        }
        #pragma unroll
        for (int kc = 0; kc < 4; ++kc) {
            short8 af0 = *(const short8*)&As[cur][l15][kc * 32 + lhi * 8];
            short8 af1 = *(const short8*)&As[cur][16 + l15][kc * 32 + lhi * 8];
            #pragma unroll
            for (int nj = 0; nj < 3; ++nj) {
                short8 bf = *(const short8*)(wtf + (size_t)((wn * 3 + nj) * 32 + ks * 4 + kc) * 512 + lane * 8);
                acc[0][nj] = __builtin_amdgcn_mfma_f32_16x16x32_bf16(af0, bf, acc[0][nj], 0, 0, 0);
                acc[1][nj] = __builtin_amdgcn_mfma_f32_16x16x32_bf16(af1, bf, acc[1][nj], 0, 0, 0);
            }
        }
        // LDS reads (lgkm) drained; in-flight global prefetch survives
        BARRIER_KEEP_VMCNT();
    }

    // epilogue: scatter into fragment-linear q/k/v (round-9 verified algebra)
    for (int mt = 0; mt < 2; ++mt) {
        const int growb = row0 + mt * 16 + lhi * 4;    // t = growb + r
        const int bI = growb >> 11;
        const int tloc = growb & 2047;
        for (int nj = 0; nj < 3; ++nj) {
            const int gcolb = wn * 48 + nj * 16;
            const int matid = gcolb >> 6;
            const int d0 = gcolb & 63;
            if (matid < 2) {
                u16* dst = matid == 0 ? qfl : kfl;
                const int g = tloc >> 4;
                const int lhid = ((d0 & 31) + l15) >> 3;
                const size_t base = ((size_t)(bI * 128 + g) * 2 + (d0 >> 5)) * 512
                                    + (size_t)lhid * 128 + (l15 & 7);
                for (int r = 0; r < 4; ++r)
                    dst[base + (size_t)(lhi * 4 + r) * 8] = bfu(acc[mt][nj][r]);
            } else {
                const int kt64 = tloc >> 6;
                const int tin = tloc & 63;
                const int kcv = tin >> 5;
                const int lhiv = (tin & 31) >> 3;
                const int e0 = tin & 7;
                const int dt = d0 >> 4;
                u16x4 pk;
                pk[0] = bfu(acc[mt][nj][0]); pk[1] = bfu(acc[mt][nj][1]);
                pk[2] = bfu(acc[mt][nj][2]); pk[3] = bfu(acc[mt][nj][3]);
                *(u16x4*)(vfl + ((size_t)((bI * 32 + kt64) * 4 + dt) * 2 + kcv) * 512
                              + (size_t)(lhiv * 16 + l15) * 8 + e0) = pk;
            }
        }
    }
}

// Flash attention, causal. Block-level split-K, 8 waves per 16-row q-tile
// (round-17 verified, byte-identical; ~7us in-situ).
__global__ __launch_bounds__(512, 4) void attn_fwd(const u16* __restrict__ qfl,
                                                   const u16* __restrict__ kfl,
                                                   const u16* __restrict__ vfl,
                                                   float* __restrict__ out) {
    __shared__ float o_lds[8][16][68];
    __shared__ float ml_lds[8][2][16];
    __shared__ u16 pl[8][16][72];
    const int tid = threadIdx.x;
    const int lane = tid & 63;
    const int w = tid >> 6;           // 0..7
    const int l15 = lane & 15, lhi = lane >> 4;
    const int idx = (int)blockIdx.x;  // 0..1023
    const int qt = 127 - (idx >> 3);  // longest q-tiles dispatched first
    const int b = idx & 7;
    const int nkt = (qt >> 2) + 1;
    const int q0 = qt * 16;

    const u16* qb = qfl + (size_t)b * 131072;
    const u16* kb = kfl + (size_t)b * 131072;
    const u16* vb = vfl + (size_t)b * 131072;

    short8 qf[2];
    #pragma unroll
    for (int kc = 0; kc < 2; ++kc)
        qf[kc] = *(const short8*)(qb + ((size_t)(qt * 2 + kc) * 64 + lane) * 8);

    float m = -1e30f, lpart = 0.f;
    f32x4 o[4];
    for (int dt = 0; dt < 4; ++dt) o[dt] = f32x4{0.f, 0.f, 0.f, 0.f};

    for (int kbi = w; kbi < nkt; kbi += 8) {
        const int k0 = kbi * 64;
        short8 kf[2][4], vf[4][2];
        #pragma unroll
        for (int kc = 0; kc < 2; ++kc)
            #pragma unroll
            for (int kt = 0; kt < 4; ++kt)
                kf[kc][kt] = *(const short8*)(kb + ((size_t)((kbi * 4 + kt) * 2 + kc) * 64 + lane) * 8);
        #pragma unroll
        for (int dt = 0; dt < 4; ++dt)
            #pragma unroll
            for (int kc = 0; kc < 2; ++kc)
                vf[dt][kc] = *(const short8*)(vb + ((size_t)((kbi * 4 + dt) * 2 + kc) * 512 + lane * 8));

        f32x4 sacc[4];
        for (int kt = 0; kt < 4; ++kt) sacc[kt] = f32x4{0.f, 0.f, 0.f, 0.f};
        #pragma unroll
        for (int kc = 0; kc < 2; ++kc)
            #pragma unroll
            for (int kt = 0; kt < 4; ++kt)
                sacc[kt] = __builtin_amdgcn_mfma_f32_16x16x32_bf16(kf[kc][kt], qf[kc], sacc[kt], 0, 0, 0);

        if (kbi == nkt - 1) {             // diagonal: causal mask
            for (int kt = 0; kt < 4; ++kt)
                for (int r = 0; r < 4; ++r) {
                    int kg = k0 + kt * 16 + lhi * 4 + r;
                    if (kg > q0 + l15) sacc[kt][r] = -3.0e38f;
                }
        }
        f32x4 mx0, mx1;
        for (int e = 0; e < 4; ++e) {
            mx0[e] = fmaxf(sacc[0][e], sacc[1][e]);
            mx1[e] = fmaxf(sacc[2][e], sacc[3][e]);
        }
        float tmax = -3.0e38f;
        for (int e = 0; e < 4; ++e) tmax = fmaxf(tmax, fmaxf(mx0[e], mx1[e]));
        tmax = fmaxf(tmax, __shfl_xor(tmax, 16));
        tmax = fmaxf(tmax, __shfl_xor(tmax, 32));
        if (!__all(tmax <= m + 8.0f)) {   // defer-max (THR=8, log2 domain)
            float mnew = fmaxf(m, tmax);
            float corr = exp2f(m - mnew);
            m = mnew;
            lpart *= corr;
            for (int r = 0; r < 4; ++r) {
                float cr = __shfl(corr, lhi * 4 + r);
                for (int dt = 0; dt < 4; ++dt) o[dt][r] *= cr;
            }
        }
        float psum = 0.f;
        for (int kt = 0; kt < 4; ++kt)
            for (int r = 0; r < 4; ++r) {
                float p = exp2f(sacc[kt][r] - m);
                sacc[kt][r] = p;
                psum += p;
            }
        lpart += psum;
        for (int kt = 0; kt < 4; ++kt) {
            u16x4 pk;
            pk[0] = bfu(sacc[kt][0]); pk[1] = bfu(sacc[kt][1]);
            pk[2] = bfu(sacc[kt][2]); pk[3] = bfu(sacc[kt][3]);
            *(u16x4*)&pl[w][l15][kt * 16 + lhi * 4] = pk;
        }
        short8 pf[2];
        #pragma unroll
        for (int kc = 0; kc < 2; ++kc)
            pf[kc] = *(const short8*)&pl[w][l15][kc * 32 + lhi * 8];
        #pragma unroll
        for (int dt = 0; dt < 4; ++dt)
            #pragma unroll
            for (int kc = 0; kc < 2; ++kc)
                o[dt] = __builtin_amdgcn_mfma_f32_16x16x32_bf16(pf[kc], vf[dt][kc], o[dt], 0, 0, 0);
    }
    float lsum = lpart;
    lsum += __shfl_xor(lsum, 16);
    lsum += __shfl_xor(lsum, 32);

    for (int dt = 0; dt < 4; ++dt)
        for (int r = 0; r < 4; ++r)
            o_lds[w][lhi * 4 + r][dt * 16 + l15] = o[dt][r];
    if (lhi == 0) {
        ml_lds[w][0][l15] = m;
        ml_lds[w][1][l15] = lsum;
    }
    __syncthreads();

    float* ob = out + ((size_t)b * Tn + q0) * Hn;
    #pragma unroll
    for (int i = 0; i < 2; ++i) {
        const int e = tid + 512 * i;      // 0..1023
        const int row = e >> 6, d = e & 63;
        float M = -3.0e38f;
        #pragma unroll
        for (int ww = 0; ww < 8; ++ww) M = fmaxf(M, ml_lds[ww][0][row]);
        float L = 0.f, acc = 0.f;
        #pragma unroll
        for (int ww = 0; ww < 8; ++ww) {
            float wgt = exp2f(ml_lds[ww][0][row] - M);
            L += ml_lds[ww][1][row] * wgt;
            acc += o_lds[ww][row][d] * wgt;
        }
        ob[(size_t)row * Hn + d] = acc / L;
    }
}

extern "C" void kernel_launch(void* const* d_in, const int* in_sizes, int n_in,
                              void* d_out, int out_size, void* d_ws, size_t ws_size,
                              hipStream_t stream) {
    const float* x = (const float*)d_in[0];
    const float* Wq = (const float*)d_in[1];
    const float* Wk = (const float*)d_in[2];
    const float* Wv = (const float*)d_in[3];
    float* out = (float*)d_out;
    char* ws = (char*)d_ws;

    u16* wtf = (u16*)ws;                                   // 384 KB
    u16* qfl = (u16*)(ws + 196608 * 2);                    // 2 MB
    u16* kfl = qfl + (size_t)Bn * 131072;                  // 2 MB
    u16* vfl = kfl + (size_t)Bn * 131072;                  // 2 MB

    const float qscale = 0.04508422002778011f;  // C^-0.5 * log2(e)
    convert_w3<<<768, 256, 0, stream>>>(Wq, Wk, Wv, wtf, qscale);
    qkv_proj<<<Mrows / 32, 256, 0, stream>>>(x, wtf, qfl, kfl, vfl);
    attn_fwd<<<1024, 512, 0, stream>>>(qfl, kfl, vfl, out);
}